// Round 2
// baseline (146.590 us; speedup 1.0000x reference)
//
#include <hip/hip_runtime.h>

// Smoother: out = max(pred, (reflect-pad moving-sum(K=501) + bias)/K)
// pred: [B=8, T=16384, C=128] fp32.
//
// Round 9 (resubmit; r9 bench died to container-infra error, not kernel):
// drop the LDS ring entirely. r8 counters (VALUBusy 14%, HBM 25%,
// Occupancy 4.9%) => latency-bound, not BW-bound. The ring caused both
// problems: (1) 64KB LDS/block capped residency at 2 waves/CU; (2) each
// global_load_lds stage forces a compiler-inserted s_waitcnt vmcnt(0) drain
// before the next ds_read batch (LLVM can't alias-disambiguate LDS DMA), so
// ~full memory latency is exposed once per 64-row chunk per wave.
// FETCH_SIZE (~40MB < 64MiB compulsory) proves the input is L3-resident, so
// re-reading the 3 streams (new @t+251, old @t-250, center @t) from global
// costs L2/L3 bandwidth we have in surplus, not HBM. Reuse distance is
// 501 rows x 64 B = 32 KB/block -> L2-friendly.
// New shape: NSEG=32 -> 2048 blocks x 1 wave, 0 LDS, <=128 VGPR
// (launch_bounds(64,4)) -> 8 blocks/CU (2 waves/SIMD, 4x r8), unroll-8
// independent global loads for ILP. Quad-row prefix (2 shfl_up) recurrence
// unchanged; numerics identical to r8.

constexpr int B    = 8;
constexpr int T    = 16384;
constexpr int C    = 128;
constexpr int K    = 501;
constexpr int CHN  = 16;              // channels per block
constexpr int NCG  = C / CHN;         // 8 channel groups
constexpr int NSEG = 32;              // segments per column
constexpr int SEGR = T / NSEG;        // 512 output rows per block

__device__ __forceinline__ int ridx(int j) {
    j = (j < 0) ? -j : j;
    return (j >= T) ? (2 * T - 2 - j) : j;
}

__global__ __launch_bounds__(64, 4) void smoother_kernel(
    const float* __restrict__ pred, const float* __restrict__ bias,
    float* __restrict__ out) {
    // 2048 blocks: b = blockIdx&7 (one batch per XCD), cg, seg.
    const int b   = blockIdx.x & 7;
    const int cg  = (blockIdx.x >> 3) & 7;
    const int seg = blockIdx.x >> 6;
    const int g0  = seg * SEGR;

    const int lane = threadIdx.x & 63;
    const int q    = lane >> 4;          // row-in-quad 0..3
    const int ch   = lane & 15;          // channel within group

    const float* pb = pred + (size_t)b * T * C + cg * CHN + ch;
    float*       ob = out  + (size_t)b * T * C + cg * CHN + ch;

    const float rk  = 1.0f / (float)K;
    const float brk = bias[0] * rk;

    // interior <=> no reflect needed anywhere in seed or slide
    const bool interior = (g0 >= 251) && (g0 + SEGR + 251 <= T);

    // ---- seed: S = sum rows [g0-250, g0+250] per channel ----
    float acc = 0.0f;
    if (interior) {
        #pragma unroll 5
        for (int i = 0; i < 125; ++i)
            acc += pb[(g0 - 250 + 4 * i + q) * C];
    } else {
        #pragma unroll 5
        for (int i = 0; i < 125; ++i)
            acc += pb[ridx(g0 - 250 + 4 * i + q) * C];
    }
    float a2 = acc + __shfl_xor(acc, 16);
    float S  = a2 + __shfl_xor(a2, 32);
    S += pb[(interior ? (g0 + 250) : ridx(g0 + 250)) * C];

    // ---- slide: SEGR/4 quad-steps (4 rows x 16 ch per step) ----
    int tn = g0 + 251 + q;   // row of vn (added moving t -> t+1)
    int to = g0 - 250 + q;   // row of vo (dropped moving t -> t+1)
    int tc = g0 + q;         // row of vc / output
    const int srcl = 48 + ch;

    if (interior) {
        #pragma unroll 8
        for (int i = 0; i < SEGR / 4; ++i) {
            const float vn = pb[tn * C];
            const float vo = pb[to * C];
            const float vc = pb[tc * C];
            const float d  = vn - vo;
            // inclusive prefix of d over the quad (Hillis-Steele, 2 shfl)
            float x = d;
            const float u1 = __shfl_up(x, 16); if (lane >= 16) x += u1;
            const float u2 = __shfl_up(x, 32); if (lane >= 32) x += u2;
            const float tot = __shfl(x, srcl);      // quad total, per channel
            const float sm  = S + (x - d);          // exclusive prefix
            const float o   = fmaxf(vc, fmaf(sm, rk, brk));
            __builtin_nontemporal_store(o, &ob[tc * C]);
            S += tot;
            tn += 4; to += 4; tc += 4;
        }
    } else {
        #pragma unroll 4
        for (int i = 0; i < SEGR / 4; ++i) {
            const float vn = pb[ridx(tn) * C];
            const float vo = pb[ridx(to) * C];
            const float vc = pb[tc * C];
            const float d  = vn - vo;
            float x = d;
            const float u1 = __shfl_up(x, 16); if (lane >= 16) x += u1;
            const float u2 = __shfl_up(x, 32); if (lane >= 32) x += u2;
            const float tot = __shfl(x, srcl);
            const float sm  = S + (x - d);
            const float o   = fmaxf(vc, fmaf(sm, rk, brk));
            __builtin_nontemporal_store(o, &ob[tc * C]);
            S += tot;
            tn += 4; to += 4; tc += 4;
        }
    }
}

extern "C" void kernel_launch(void* const* d_in, const int* in_sizes, int n_in,
                              void* d_out, int out_size, void* d_ws, size_t ws_size,
                              hipStream_t stream) {
    const float* pred = (const float*)d_in[0];
    const float* bias = (const float*)d_in[1];
    float*       out  = (float*)d_out;

    const int blocks = B * NCG * NSEG;   // 2048
    smoother_kernel<<<blocks, 64, 0, stream>>>(pred, bias, out);
}

// Round 3
// 132.824 us; speedup vs baseline: 1.1036x; 1.1036x over previous
//
#include <hip/hip_runtime.h>

// Smoother: out = max(pred, (reflect-pad moving-sum(K=501) + bias)/K)
// pred: [B=8, T=16384, C=128] fp32.
//
// Round 10: shared LDS ring, reg-staged. r9 post-mortem: issued vector-mem
// bytes (267 MB read + 76 MB write) / 57 us = 6.0 TB/s = the per-CU
// load-return ceiling (~10 B/cy/CU) -- r9 was AT its roofline; HBM only 40%.
// Fix = read each global byte once again (LDS ring), but without r8's
// pathologies:
//  * 256-thread blocks, 4 waves SHARE one 39 KB ring (wave owns 4 of 16 ch,
//    all waves walk rows in lockstep) -> 4 blocks/CU = 16 waves/CU.
//  * staging is global_load->reg->ds_write (NOT global_load_lds), T14 split:
//    issue chunk i+17's loads, compute chunk i from ring, vmcnt-wait,
//    ds_write, one barrier per 32-row chunk. No alias-blind vmcnt(0) drains.
//  * ring row stride 17 dwords -> ds_read pattern <=2-way bank (free, m136).
//  * 16-row steps, 4-shuffle Hillis-Steele prefix for the window recurrence
//    (~2.4 instr/row vs r9's 6.3).
// Issued global bytes: reads 8*16*8 blocks * 1536 rows * 64 B = 101 MB
// (+64 MB writes) = 165 MB -> ~27 us at the 6.1 TB/s issue path; the 3
// window streams read from LDS (~250 MB at 69 TB/s, off critical path).

constexpr int B     = 8;
constexpr int T     = 16384;
constexpr int C     = 128;
constexpr int K     = 501;
constexpr int CHN   = 16;             // channels per block
constexpr int NCG   = C / CHN;        // 8 channel groups
constexpr int NSEG  = 16;             // segments per column
constexpr int SEGR  = T / NSEG;       // 1024 output rows per block
constexpr int CHK   = 32;             // staging chunk rows
constexpr int RROWS = 576;            // ring rows = 18 chunks
constexpr int RPAD  = 17;             // dwords per ring row (16 ch + 1 pad)
constexpr int RSZ   = RROWS * RPAD;   // 9792 dwords = 39168 B
constexpr int MARG  = 256;            // rows staged before g0
constexpr int PRO   = 17;             // prologue chunks (rows g0-256..g0+287)
constexpr int NCHK  = 48;             // total chunks (rows g0-256..g0+1279)

__device__ __forceinline__ int ridx(int j) {
    j = (j < 0) ? -j : j;
    return (j >= T) ? (2 * T - 2 - j) : j;
}

__global__ __launch_bounds__(256, 4) void smoother_kernel(
    const float* __restrict__ pred, const float* __restrict__ bias,
    float* __restrict__ out) {
    __shared__ float ring[RSZ];       // 39168 B -> 4 blocks/CU

    // 1024 blocks: b = blockIdx&7 (batch -> XCD), cg, seg.
    const int b   = blockIdx.x & 7;
    const int cg  = (blockIdx.x >> 3) & 7;
    const int seg = blockIdx.x >> 6;
    const int g0  = seg * SEGR;
    const int jstart = g0 - MARG;

    const int tid  = threadIdx.x;
    const int lane = tid & 63;
    const int w    = tid >> 6;        // wave 0..3
    const int rowq = lane >> 2;       // row-in-step 0..15
    const int cs   = lane & 3;        // channel within wave's 4
    const int ch   = w * 4 + cs;      // channel within group 0..15

    // staging mapping: 256 threads cover 32 rows x 8 channel-pairs
    const int srow = tid >> 3;        // 0..31
    const int chp  = tid & 7;         // channel pair 0..7

    const float* pb = pred + (size_t)b * T * C + cg * CHN;
    float*       ob = out  + (size_t)b * T * C + cg * CHN;

    const float rk  = 1.0f / (float)K;
    const float brk = bias[0] * rk;

    // ---- prologue: stage chunks 0..16 (rows jstart .. g0+287) ----
    {
        float2 pv0[PRO];
        #pragma unroll
        for (int m = 0; m < PRO; ++m) {
            const int jr = ridx(jstart + m * CHK + srow);
            pv0[m] = *reinterpret_cast<const float2*>(
                pb + (size_t)jr * C + chp * 2);
        }
        #pragma unroll
        for (int m = 0; m < PRO; ++m) {
            const int p = m * CHK + srow;          // < 576, no wrap
            float* d = &ring[p * RPAD + chp * 2];
            d[0] = pv0[m].x; d[1] = pv0[m].y;
        }
    }
    __syncthreads();

    // ---- seed: S = sum rows [g0-250, g0+250] (ring rows 6..506) ----
    float acc = 0.0f;
    #pragma unroll 8
    for (int k2 = 0; k2 < 31; ++k2)
        acc += ring[(6 + rowq + 16 * k2) * RPAD + ch];
    if (rowq <= 4) acc += ring[(502 + rowq) * RPAD + ch];
    acc += __shfl_xor(acc, 4);
    acc += __shfl_xor(acc, 8);
    acc += __shfl_xor(acc, 16);
    acc += __shfl_xor(acc, 32);
    float S = acc;                    // window sum at row g0, per channel

    // ---- slide: 32 chunk-iters x 2 steps x 16 rows ----
    // ring dword indices for the 3 streams (stride RPAD rows, wrap at RSZ)
    int idxn = (507 + rowq) * RPAD + ch;   // row t+251
    int idxo = (6   + rowq) * RPAD + ch;   // row t-250
    int idxc = (256 + rowq) * RPAD + ch;   // row t (center)
    float* op = ob + (size_t)(g0 + rowq) * C + ch;

    int pm = PRO * CHK;                    // 544: ring phase of next chunk
    float2 pv;

    for (int i = 0; i < SEGR / CHK; ++i) {
        const bool do_stage = (i + PRO) < NCHK;   // i <= 30
        if (do_stage) {
            const int jr = ridx(jstart + (i + PRO) * CHK + srow);
            pv = *reinterpret_cast<const float2*>(
                pb + (size_t)jr * C + chp * 2);
        }

        #pragma unroll
        for (int s = 0; s < 2; ++s) {
            const float vn = ring[idxn];
            const float vo = ring[idxo];
            const float vc = ring[idxc];
            const float d  = vn - vo;
            // inclusive prefix of d over 16 rows (Hillis-Steele, 4 shfl)
            float x = d;
            const float u1 = __shfl_up(x, 4);  if (lane >= 4)  x += u1;
            const float u2 = __shfl_up(x, 8);  if (lane >= 8)  x += u2;
            const float u3 = __shfl_up(x, 16); if (lane >= 16) x += u3;
            const float u4 = __shfl_up(x, 32); if (lane >= 32) x += u4;
            const float tot = __shfl(x, 60 + cs);   // step total, per channel
            const float sm  = S + (x - d);          // exclusive prefix
            const float o   = fmaxf(vc, fmaf(sm, rk, brk));
            __builtin_nontemporal_store(o, op);
            S += tot;
            idxn += 16 * RPAD; if (idxn >= RSZ) idxn -= RSZ;
            idxo += 16 * RPAD; if (idxo >= RSZ) idxo -= RSZ;
            idxc += 16 * RPAD; if (idxc >= RSZ) idxc -= RSZ;
            op += 16 * C;
        }

        if (do_stage) {
            int p = pm + srow; if (p >= RROWS) p -= RROWS;
            float* d = &ring[p * RPAD + chp * 2];
            d[0] = pv.x; d[1] = pv.y;
            pm += CHK; if (pm >= RROWS) pm -= RROWS;
        }
        __syncthreads();
    }
}

extern "C" void kernel_launch(void* const* d_in, const int* in_sizes, int n_in,
                              void* d_out, int out_size, void* d_ws, size_t ws_size,
                              hipStream_t stream) {
    const float* pred = (const float*)d_in[0];
    const float* bias = (const float*)d_in[1];
    float*       out  = (float*)d_out;

    const int blocks = B * NCG * NSEG;   // 1024
    smoother_kernel<<<blocks, 256, 0, stream>>>(pred, bias, out);
}

// Round 4
// 129.881 us; speedup vs baseline: 1.1286x; 1.0227x over previous
//
#include <hip/hip_runtime.h>

// Smoother: out = max(pred, (reflect-pad moving-sum(K=501) + bias)/K)
// pred: [B=8, T=16384, C=128] fp32.
//
// Round 11: float4 no-LDS. r10 post-mortem: the ring cut FETCH to ~48 MB
// (compulsory) but spent the gain on LDS instr + 2.6M bank conflicts +
// per-chunk barrier/vmcnt lockstep, and its 16-ch blocks caused 1.45x HBM
// write amplification (WRITE 97 MB vs 67 ideal: each 128 B line is written
// 64 B at a time by two different cg-blocks). Still ~30% on every pipe =
// latency/issue-bound.
// Fix: r9's barrier-free 3-stream structure, vectorized float4:
//  * each lane owns 4 channels; wave = 8 rows x 8 quads; CHN=32 -> every
//    store instruction writes 8 FULL 128 B lines (no partial-line RMW).
//  * loads are global_load_dwordx4; 4x fewer mem instructions than r9; the
//    scalar-request path was r9's 6 TB/s ceiling, not a byte ceiling.
//  * vn (t+251) pulls the line into L2; vc (t) and vo (t-250) re-hit L2/L3
//    at 34.5 TB/s aggregate -- re-read amplification stays off HBM.
//  * prefix chain now 3 levels (8-row steps): shfl_up 8/16/32 + bcast.
//  * no LDS, no barriers, 2048 one-wave blocks (NSEG=64), b=blockIdx&7
//    keeps each XCD on one batch's 8 MB slice.

constexpr int B    = 8;
constexpr int T    = 16384;
constexpr int C    = 128;
constexpr int K    = 501;
constexpr int CHN  = 32;              // channels per block (one full L2 line/row)
constexpr int NCG  = C / CHN;         // 4 channel groups
constexpr int NSEG = 64;              // segments per column
constexpr int SEGR = T / NSEG;        // 256 output rows per block
constexpr int RPR  = C / 4;           // 32 float4 per row

typedef float f32x4 __attribute__((ext_vector_type(4)));

__device__ __forceinline__ int ridx(int j) {
    j = (j < 0) ? -j : j;
    return (j >= T) ? (2 * T - 2 - j) : j;
}

__device__ __forceinline__ float4 shfl_up4(const float4 v, int d) {
    float4 r;
    r.x = __shfl_up(v.x, d); r.y = __shfl_up(v.y, d);
    r.z = __shfl_up(v.z, d); r.w = __shfl_up(v.w, d);
    return r;
}
__device__ __forceinline__ float4 shfl_xor4(const float4 v, int m) {
    float4 r;
    r.x = __shfl_xor(v.x, m); r.y = __shfl_xor(v.y, m);
    r.z = __shfl_xor(v.z, m); r.w = __shfl_xor(v.w, m);
    return r;
}
__device__ __forceinline__ float4 shfl4(const float4 v, int src) {
    float4 r;
    r.x = __shfl(v.x, src); r.y = __shfl(v.y, src);
    r.z = __shfl(v.z, src); r.w = __shfl(v.w, src);
    return r;
}

__global__ __launch_bounds__(64) void smoother_kernel(
    const float* __restrict__ pred, const float* __restrict__ bias,
    float* __restrict__ out) {
    // 2048 blocks: b = blockIdx&7 (batch -> XCD), cg (2b), seg (6b).
    const int b   = blockIdx.x & 7;
    const int cg  = (blockIdx.x >> 3) & (NCG - 1);
    const int seg = blockIdx.x >> 5;
    const int g0  = seg * SEGR;

    const int lane = threadIdx.x & 63;
    const int rowq = lane >> 3;          // row-in-step 0..7
    const int cq   = lane & 7;           // channel-quad 0..7

    const float4* p4 = reinterpret_cast<const float4*>(
        pred + (size_t)b * T * C + cg * CHN) + cq;
    float4* o4 = reinterpret_cast<float4*>(
        out + (size_t)b * T * C + cg * CHN) + cq;
    // row j lives at p4[j * RPR]

    const float rk  = 1.0f / (float)K;
    const float brk = bias[0] * rk;

    const bool interior = (g0 >= 251) && (g0 + SEGR + 251 <= T);

    // ---- seed: S = sum rows [g0-250, g0+250] per channel ----
    float4 acc = make_float4(0.f, 0.f, 0.f, 0.f);
    const int j0 = g0 - 250 + rowq;
    if (interior) {
        #pragma unroll 8
        for (int k = 0; k < 62; ++k)
            acc += p4[(j0 + 8 * k) * RPR];
        if (rowq <= 4) acc += p4[(j0 + 496) * RPR];
    } else {
        #pragma unroll 8
        for (int k = 0; k < 62; ++k)
            acc += p4[ridx(j0 + 8 * k) * RPR];
        if (rowq <= 4) acc += p4[ridx(j0 + 496) * RPR];
    }
    acc += shfl_xor4(acc, 8);
    acc += shfl_xor4(acc, 16);
    acc += shfl_xor4(acc, 32);
    float4 S = acc;                      // window sum at row g0, per channel

    // ---- slide: SEGR/8 steps of 8 rows ----
    int t = g0 + rowq;
    const int bsrc = 56 + cq;            // lane holding rowq=7 for my quad

    if (interior) {
        #pragma unroll 4
        for (int s = 0; s < SEGR / 8; ++s) {
            const float4 vn = p4[(t + 251) * RPR];
            const float4 vo = p4[(t - 250) * RPR];
            const float4 vc = p4[t * RPR];
            float4 d = vn;
            d.x -= vo.x; d.y -= vo.y; d.z -= vo.z; d.w -= vo.w;
            // inclusive prefix of d over 8 rows (Hillis-Steele, 3 levels)
            float4 x = d;
            float4 u;
            u = shfl_up4(x, 8);  if (lane >= 8)  { x.x += u.x; x.y += u.y; x.z += u.z; x.w += u.w; }
            u = shfl_up4(x, 16); if (lane >= 16) { x.x += u.x; x.y += u.y; x.z += u.z; x.w += u.w; }
            u = shfl_up4(x, 32); if (lane >= 32) { x.x += u.x; x.y += u.y; x.z += u.z; x.w += u.w; }
            const float4 tot = shfl4(x, bsrc);      // step total, per channel
            float4 o;
            o.x = fmaxf(vc.x, fmaf(S.x + (x.x - d.x), rk, brk));
            o.y = fmaxf(vc.y, fmaf(S.y + (x.y - d.y), rk, brk));
            o.z = fmaxf(vc.z, fmaf(S.z + (x.z - d.z), rk, brk));
            o.w = fmaxf(vc.w, fmaf(S.w + (x.w - d.w), rk, brk));
            __builtin_nontemporal_store(*reinterpret_cast<f32x4*>(&o),
                                        reinterpret_cast<f32x4*>(&o4[t * RPR]));
            S.x += tot.x; S.y += tot.y; S.z += tot.z; S.w += tot.w;
            t += 8;
        }
    } else {
        #pragma unroll 4
        for (int s = 0; s < SEGR / 8; ++s) {
            const float4 vn = p4[ridx(t + 251) * RPR];
            const float4 vo = p4[ridx(t - 250) * RPR];
            const float4 vc = p4[t * RPR];
            float4 d = vn;
            d.x -= vo.x; d.y -= vo.y; d.z -= vo.z; d.w -= vo.w;
            float4 x = d;
            float4 u;
            u = shfl_up4(x, 8);  if (lane >= 8)  { x.x += u.x; x.y += u.y; x.z += u.z; x.w += u.w; }
            u = shfl_up4(x, 16); if (lane >= 16) { x.x += u.x; x.y += u.y; x.z += u.z; x.w += u.w; }
            u = shfl_up4(x, 32); if (lane >= 32) { x.x += u.x; x.y += u.y; x.z += u.z; x.w += u.w; }
            const float4 tot = shfl4(x, bsrc);
            float4 o;
            o.x = fmaxf(vc.x, fmaf(S.x + (x.x - d.x), rk, brk));
            o.y = fmaxf(vc.y, fmaf(S.y + (x.y - d.y), rk, brk));
            o.z = fmaxf(vc.z, fmaf(S.z + (x.z - d.z), rk, brk));
            o.w = fmaxf(vc.w, fmaf(S.w + (x.w - d.w), rk, brk));
            __builtin_nontemporal_store(*reinterpret_cast<f32x4*>(&o),
                                        reinterpret_cast<f32x4*>(&o4[t * RPR]));
            S.x += tot.x; S.y += tot.y; S.z += tot.z; S.w += tot.w;
            t += 8;
        }
    }
}

extern "C" void kernel_launch(void* const* d_in, const int* in_sizes, int n_in,
                              void* d_out, int out_size, void* d_ws, size_t ws_size,
                              hipStream_t stream) {
    const float* pred = (const float*)d_in[0];
    const float* bias = (const float*)d_in[1];
    float*       out  = (float*)d_out;

    const int blocks = B * NCG * NSEG;   // 2048
    smoother_kernel<<<blocks, 64, 0, stream>>>(pred, bias, out);
}